// Round 3
// baseline (543.948 us; speedup 1.0000x reference)
//
#include <hip/hip_runtime.h>
#include <hip/hip_fp16.h>
#include <cmath>

#define IMG_H 512
#define IMG_W 512
#define TILE_X 64
#define TILE_Y 32
#define LH 42          // TILE_Y + 10 halo rows of horizontal-conv output
#define NBLOCKS (8 * 16 * 32)
#define NPIX (8 * 4 * 512 * 512)

struct Weights { float w[11]; };

// LDS: 2 packed half2 planes + 1 f32 plane = 3*42*64*4 = 31.5KB -> 4 blocks/CU
// 4 blocks x 8 waves = 32 waves/CU (threads-capped 100% occupancy), VGPR<=64.
__global__ __launch_bounds__(512, 8)
void ssim_tile_kernel(const float* __restrict__ pred,
                      const float* __restrict__ targ,
                      float* __restrict__ partials,
                      Weights wt)
{
    __shared__ __half2 hA[LH * TILE_X];  // (conv(p),  conv(t))   f16x2  10.5KB
    __shared__ __half2 hB[LH * TILE_X];  // (conv(pp), conv(tt))  f16x2  10.5KB
    __shared__ float   hC[LH * TILE_X];  // conv(pt)  kept f32 (sigma12 is delicate)
    __shared__ float wsum[8];

    const int tid = threadIdx.x;
    const int x0 = blockIdx.x * TILE_X;
    const int y0 = blockIdx.y * TILE_Y;
    const int plane = blockIdx.z;
    const float* __restrict__ P = pred + (size_t)plane * IMG_H * IMG_W;
    const float* __restrict__ T = targ + (size_t)plane * IMG_H * IMG_W;

    // ---- Phase B: horizontal 11-tap pass directly from global memory ----
    // 42 rows x 16 col-groups (4 outputs each) = 672 work items.
    for (int i = tid; i < LH * 16; i += 512) {
        int r = i >> 4;
        int c4 = (i & 15) * 4;
        int gy = y0 + r - 5;
        float p[20], t[20];
        if ((unsigned)gy < IMG_H) {
            const float* rp = P + gy * IMG_W;
            const float* rt = T + gy * IMG_W;
            int gx0 = x0 + c4 - 8;                 // 16B aligned
            if (gx0 >= 0 && gx0 + 20 <= IMG_W) {   // interior fast path
                #pragma unroll
                for (int q = 0; q < 5; ++q) {
                    *(float4*)&p[q * 4] = *(const float4*)&rp[gx0 + q * 4];
                    *(float4*)&t[q * 4] = *(const float4*)&rt[gx0 + q * 4];
                }
            } else {                               // image x-edge: guarded scalar
                #pragma unroll
                for (int q = 0; q < 20; ++q) {
                    int gx = gx0 + q;
                    bool v = (unsigned)gx < IMG_W;
                    p[q] = v ? rp[gx] : 0.f;
                    t[q] = v ? rt[gx] : 0.f;
                }
            }
        } else {
            #pragma unroll
            for (int q = 0; q < 20; ++q) { p[q] = 0.f; t[q] = 0.f; }
        }

        float s1[4], s2[4], s11[4], s22[4], s12[4];
        #pragma unroll
        for (int o = 0; o < 4; ++o) { s1[o]=0.f; s2[o]=0.f; s11[o]=0.f; s22[o]=0.f; s12[o]=0.f; }
        #pragma unroll
        for (int k = 0; k < 11; ++k) {
            float w = wt.w[k];
            #pragma unroll
            for (int o = 0; o < 4; ++o) {
                float pv = p[o + 3 + k], tv = t[o + 3 + k];
                float wp = w * pv, wtv = w * tv;
                s1[o]  += wp;
                s2[o]  += wtv;
                s11[o] += wp * pv;
                s22[o] += wtv * tv;
                s12[o] += wp * tv;
            }
        }
        int ho = r * TILE_X + c4;
        #pragma unroll
        for (int o = 0; o < 4; ++o) {
            hA[ho + o] = __floats2half2_rn(s1[o],  s2[o]);   // adjacent b32 -> b128 merge
            hB[ho + o] = __floats2half2_rn(s11[o], s22[o]);
        }
        *(float4*)&hC[ho] = make_float4(s12[0], s12[1], s12[2], s12[3]);
    }
    __syncthreads();

    // ---- Phase C: vertical 11-tap pass (packed f16x2) + SSIM, 4 rows/thread ----
    const int c  = tid & 63;          // output column (conflict-free)
    const int r0 = (tid >> 6) * 4;    // 8 row-groups x 4 rows = 32 rows exactly
    __half2 wh[11];
    #pragma unroll
    for (int k = 0; k < 11; ++k) wh[k] = __float2half2_rn(wt.w[k]);

    __half2 aA[4], aB[4];
    float a12[4];
    #pragma unroll
    for (int o = 0; o < 4; ++o) {
        aA[o] = __float2half2_rn(0.f);
        aB[o] = __float2half2_rn(0.f);
        a12[o] = 0.f;
    }

    #pragma unroll
    for (int j = 0; j < 14; ++j) {     // rows r0 .. r0+13 cover outputs r0..r0+3
        int hr = (r0 + j) * TILE_X + c;
        __half2 vA = hA[hr];
        __half2 vB = hB[hr];
        float  v12 = hC[hr];
        #pragma unroll
        for (int o = 0; o < 4; ++o) {
            int k = j - o;
            if (k >= 0 && k < 11) {    // compile-time resolved
                aA[o] = __hfma2(wh[k], vA, aA[o]);   // v_pk_fma_f16: both planes at once
                aB[o] = __hfma2(wh[k], vB, aB[o]);
                a12[o] = fmaf(wt.w[k], v12, a12[o]);
            }
        }
    }

    float lsum = 0.f;
    #pragma unroll
    for (int o = 0; o < 4; ++o) {
        float mu1 = __low2float(aA[o]);
        float mu2 = __high2float(aA[o]);
        float e11 = __low2float(aB[o]);
        float e22 = __high2float(aB[o]);
        float m11 = mu1 * mu1, m22 = mu2 * mu2, m12 = mu1 * mu2;
        float sg1 = e11 - m11;
        float sg2 = e22 - m22;
        float sg12 = a12[o] - m12;
        float num = (2.f * m12 + 1e-4f) * (2.f * sg12 + 9e-4f);
        float den = (m11 + m22 + 1e-4f) * (sg1 + sg2 + 9e-4f);
        lsum += __fdividef(num, den);
    }

    // ---- Block reduction (deterministic) ----
    #pragma unroll
    for (int off = 32; off > 0; off >>= 1) lsum += __shfl_down(lsum, off);
    if ((tid & 63) == 0) wsum[tid >> 6] = lsum;
    __syncthreads();
    if (tid == 0) {
        float bsum = 0.f;
        #pragma unroll
        for (int wv = 0; wv < 8; ++wv) bsum += wsum[wv];
        partials[(blockIdx.z * gridDim.y + blockIdx.y) * gridDim.x + blockIdx.x] = bsum;
    }
}

__global__ void ssim_finalize(const float* __restrict__ partials, float* __restrict__ out)
{
    __shared__ double red[256];
    double s = 0.0;
    for (int i = threadIdx.x; i < NBLOCKS; i += 256) s += (double)partials[i];
    red[threadIdx.x] = s;
    __syncthreads();
    for (int stride = 128; stride > 0; stride >>= 1) {
        if ((int)threadIdx.x < stride) red[threadIdx.x] += red[threadIdx.x + stride];
        __syncthreads();
    }
    if (threadIdx.x == 0) out[0] = (float)(1.0 - red[0] / (double)NPIX);
}

extern "C" void kernel_launch(void* const* d_in, const int* in_sizes, int n_in,
                              void* d_out, int out_size, void* d_ws, size_t ws_size,
                              hipStream_t stream) {
    const float* pred = (const float*)d_in[0];
    const float* targ = (const float*)d_in[1];
    float* out = (float*)d_out;
    float* partials = (float*)d_ws;   // 4096 floats = 16KB, every slot written each call

    Weights wt;
    {
        float g[11];
        float s = 0.f;
        for (int i = 0; i < 11; ++i) {
            float d = (float)(i - 5);
            g[i] = expf(-d * d / (2.f * 1.5f * 1.5f));
            s += g[i];
        }
        for (int i = 0; i < 11; ++i) wt.w[i] = g[i] / s;
    }

    dim3 grid(IMG_W / TILE_X, IMG_H / TILE_Y, 32);   // (8, 16, 32) = 4096 blocks
    ssim_tile_kernel<<<grid, 512, 0, stream>>>(pred, targ, partials, wt);
    ssim_finalize<<<1, 256, 0, stream>>>(partials, out);
}

// Round 4
// 83.185 us; speedup vs baseline: 6.5390x; 6.5390x over previous
//
#include <hip/hip_runtime.h>
#include <hip/hip_fp16.h>
#include <cmath>

#define IMG_H 512
#define IMG_W 512
#define TILE_X 64
#define TILE_Y 32
#define LH 42          // TILE_Y + 10 halo rows of horizontal-conv output
#define NBLOCKS (8 * 16 * 32)
#define NPIX (8 * 4 * 512 * 512)

struct Weights { float w[11]; };

// LDS: 2 packed half2 planes + 1 f32 plane = 3*42*64*4 = 31.5KB.
// __launch_bounds__(512,4): VGPR cap 128 — round 2 measured 56 VGPR for this
// Phase B, so no spill; at <=64 VGPR the HW can still co-schedule 4 blocks/CU
// (32 waves) since LDS allows 4. DO NOT use (512,8): it forces VGPR=32 and
// spills Phase B's 40-reg window to scratch (round 3: 790MB fetch, 1.5GB write).
__global__ __launch_bounds__(512, 4)
void ssim_tile_kernel(const float* __restrict__ pred,
                      const float* __restrict__ targ,
                      float* __restrict__ partials,
                      Weights wt)
{
    __shared__ __half2 hA[LH * TILE_X];  // (conv(p),  conv(t))   f16x2  10.5KB
    __shared__ __half2 hB[LH * TILE_X];  // (conv(pp), conv(tt))  f16x2  10.5KB
    __shared__ float   hC[LH * TILE_X];  // conv(pt)  kept f32 (sigma12 is delicate)
    __shared__ float wsum[8];

    const int tid = threadIdx.x;
    const int x0 = blockIdx.x * TILE_X;
    const int y0 = blockIdx.y * TILE_Y;
    const int plane = blockIdx.z;
    const float* __restrict__ P = pred + (size_t)plane * IMG_H * IMG_W;
    const float* __restrict__ T = targ + (size_t)plane * IMG_H * IMG_W;

    // ---- Phase B: horizontal 11-tap pass directly from global memory ----
    // 42 rows x 16 col-groups (4 outputs each) = 672 work items.
    for (int i = tid; i < LH * 16; i += 512) {
        int r = i >> 4;
        int c4 = (i & 15) * 4;
        int gy = y0 + r - 5;
        float p[20], t[20];
        if ((unsigned)gy < IMG_H) {
            const float* rp = P + gy * IMG_W;
            const float* rt = T + gy * IMG_W;
            int gx0 = x0 + c4 - 8;                 // 16B aligned
            if (gx0 >= 0 && gx0 + 20 <= IMG_W) {   // interior fast path
                #pragma unroll
                for (int q = 0; q < 5; ++q) {
                    *(float4*)&p[q * 4] = *(const float4*)&rp[gx0 + q * 4];
                    *(float4*)&t[q * 4] = *(const float4*)&rt[gx0 + q * 4];
                }
            } else {                               // image x-edge: guarded scalar
                #pragma unroll
                for (int q = 0; q < 20; ++q) {
                    int gx = gx0 + q;
                    bool v = (unsigned)gx < IMG_W;
                    p[q] = v ? rp[gx] : 0.f;
                    t[q] = v ? rt[gx] : 0.f;
                }
            }
        } else {
            #pragma unroll
            for (int q = 0; q < 20; ++q) { p[q] = 0.f; t[q] = 0.f; }
        }

        float s1[4], s2[4], s11[4], s22[4], s12[4];
        #pragma unroll
        for (int o = 0; o < 4; ++o) { s1[o]=0.f; s2[o]=0.f; s11[o]=0.f; s22[o]=0.f; s12[o]=0.f; }
        #pragma unroll
        for (int k = 0; k < 11; ++k) {
            float w = wt.w[k];
            #pragma unroll
            for (int o = 0; o < 4; ++o) {
                float pv = p[o + 3 + k], tv = t[o + 3 + k];
                float wp = w * pv, wtv = w * tv;
                s1[o]  += wp;
                s2[o]  += wtv;
                s11[o] += wp * pv;
                s22[o] += wtv * tv;
                s12[o] += wp * tv;
            }
        }
        int ho = r * TILE_X + c4;
        #pragma unroll
        for (int o = 0; o < 4; ++o) {
            hA[ho + o] = __floats2half2_rn(s1[o],  s2[o]);
            hB[ho + o] = __floats2half2_rn(s11[o], s22[o]);
        }
        *(float4*)&hC[ho] = make_float4(s12[0], s12[1], s12[2], s12[3]);
    }
    __syncthreads();

    // ---- Phase C: vertical 11-tap pass (packed f16x2) + SSIM, 4 rows/thread ----
    const int c  = tid & 63;          // output column (conflict-free)
    const int r0 = (tid >> 6) * 4;    // 8 row-groups x 4 rows = 32 rows exactly
    __half2 wh[11];
    #pragma unroll
    for (int k = 0; k < 11; ++k) wh[k] = __float2half2_rn(wt.w[k]);

    __half2 aA[4], aB[4];
    float a12[4];
    #pragma unroll
    for (int o = 0; o < 4; ++o) {
        aA[o] = __float2half2_rn(0.f);
        aB[o] = __float2half2_rn(0.f);
        a12[o] = 0.f;
    }

    #pragma unroll
    for (int j = 0; j < 14; ++j) {     // rows r0 .. r0+13 cover outputs r0..r0+3
        int hr = (r0 + j) * TILE_X + c;
        __half2 vA = hA[hr];
        __half2 vB = hB[hr];
        float  v12 = hC[hr];
        #pragma unroll
        for (int o = 0; o < 4; ++o) {
            int k = j - o;
            if (k >= 0 && k < 11) {    // compile-time resolved
                aA[o] = __hfma2(wh[k], vA, aA[o]);   // v_pk_fma_f16: both planes at once
                aB[o] = __hfma2(wh[k], vB, aB[o]);
                a12[o] = fmaf(wt.w[k], v12, a12[o]);
            }
        }
    }

    float lsum = 0.f;
    #pragma unroll
    for (int o = 0; o < 4; ++o) {
        float mu1 = __low2float(aA[o]);
        float mu2 = __high2float(aA[o]);
        float e11 = __low2float(aB[o]);
        float e22 = __high2float(aB[o]);
        float m11 = mu1 * mu1, m22 = mu2 * mu2, m12 = mu1 * mu2;
        float sg1 = e11 - m11;
        float sg2 = e22 - m22;
        float sg12 = a12[o] - m12;
        float num = (2.f * m12 + 1e-4f) * (2.f * sg12 + 9e-4f);
        float den = (m11 + m22 + 1e-4f) * (sg1 + sg2 + 9e-4f);
        lsum += __fdividef(num, den);
    }

    // ---- Block reduction (deterministic) ----
    #pragma unroll
    for (int off = 32; off > 0; off >>= 1) lsum += __shfl_down(lsum, off);
    if ((tid & 63) == 0) wsum[tid >> 6] = lsum;
    __syncthreads();
    if (tid == 0) {
        float bsum = 0.f;
        #pragma unroll
        for (int wv = 0; wv < 8; ++wv) bsum += wsum[wv];
        partials[(blockIdx.z * gridDim.y + blockIdx.y) * gridDim.x + blockIdx.x] = bsum;
    }
}

__global__ void ssim_finalize(const float* __restrict__ partials, float* __restrict__ out)
{
    __shared__ double red[256];
    double s = 0.0;
    for (int i = threadIdx.x; i < NBLOCKS; i += 256) s += (double)partials[i];
    red[threadIdx.x] = s;
    __syncthreads();
    for (int stride = 128; stride > 0; stride >>= 1) {
        if ((int)threadIdx.x < stride) red[threadIdx.x] += red[threadIdx.x + stride];
        __syncthreads();
    }
    if (threadIdx.x == 0) out[0] = (float)(1.0 - red[0] / (double)NPIX);
}

extern "C" void kernel_launch(void* const* d_in, const int* in_sizes, int n_in,
                              void* d_out, int out_size, void* d_ws, size_t ws_size,
                              hipStream_t stream) {
    const float* pred = (const float*)d_in[0];
    const float* targ = (const float*)d_in[1];
    float* out = (float*)d_out;
    float* partials = (float*)d_ws;   // 4096 floats = 16KB, every slot written each call

    Weights wt;
    {
        float g[11];
        float s = 0.f;
        for (int i = 0; i < 11; ++i) {
            float d = (float)(i - 5);
            g[i] = expf(-d * d / (2.f * 1.5f * 1.5f));
            s += g[i];
        }
        for (int i = 0; i < 11; ++i) wt.w[i] = g[i] / s;
    }

    dim3 grid(IMG_W / TILE_X, IMG_H / TILE_Y, 32);   // (8, 16, 32) = 4096 blocks
    ssim_tile_kernel<<<grid, 512, 0, stream>>>(pred, targ, partials, wt);
    ssim_finalize<<<1, 256, 0, stream>>>(partials, out);
}

// Round 6
// 79.489 us; speedup vs baseline: 6.8430x; 1.0465x over previous
//
#include <hip/hip_runtime.h>
#include <cmath>

#define IMG_H 512
#define IMG_W 512
#define TILE_X 64
#define TILE_Y 32
#define LH 42          // TILE_Y + 10 halo rows of horizontal-conv output
#define NBLOCKS (8 * 16 * 32)
#define NPIX (8 * 4 * 512 * 512)

struct Weights { float w[11]; };

// Round-to-nearest-even f32 -> bf16 (as uint16 in high position semantics)
static __device__ __forceinline__ unsigned bf16_rne(float x) {
    unsigned u = __float_as_uint(x);
    u += 0x7FFFu + ((u >> 16) & 1u);   // RNE (inputs here are finite, non-NaN)
    return u >> 16;
}
// Pack two f32 into one bf16x2 word: a -> low16, b -> high16
static __device__ __forceinline__ unsigned pack_bf16x2(float a, float b) {
    return bf16_rne(a) | (bf16_rne(b) << 16);
}

// LDS: hAB (2 bf16x2 planes, uint2) 21.0KB + hC (f32) 10.5KB = 32.3KB -> 4 blocks/CU.
// ALL register arithmetic stays f32 (r4's __half2 register state caused scratch
// spills: WRITE_SIZE 0.13MB -> 20.7MB). Storage-only packing; unpack is bit-ops.
__global__ __launch_bounds__(512, 4)
void ssim_tile_kernel(const float* __restrict__ pred,
                      const float* __restrict__ targ,
                      float* __restrict__ partials,
                      Weights wt)
{
    __shared__ uint2 hAB[LH * TILE_X];   // .x = (h1,h2) bf16x2, .y = (h11,h22) bf16x2
    __shared__ float hC[LH * TILE_X];    // conv(pt) kept f32 (sigma12 is delicate)
    __shared__ float wsum[8];

    const int tid = threadIdx.x;
    const int x0 = blockIdx.x * TILE_X;
    const int y0 = blockIdx.y * TILE_Y;
    const int plane = blockIdx.z;
    const float* __restrict__ P = pred + (size_t)plane * IMG_H * IMG_W;
    const float* __restrict__ T = targ + (size_t)plane * IMG_H * IMG_W;

    // ---- Phase B: horizontal 11-tap pass directly from global memory ----
    // 42 rows x 16 col-groups (4 outputs each) = 672 work items.
    for (int i = tid; i < LH * 16; i += 512) {
        int r = i >> 4;
        int c4 = (i & 15) * 4;
        int gy = y0 + r - 5;
        float p[20], t[20];
        if ((unsigned)gy < IMG_H) {
            const float* rp = P + gy * IMG_W;
            const float* rt = T + gy * IMG_W;
            int gx0 = x0 + c4 - 8;                 // 16B aligned
            if (gx0 >= 0 && gx0 + 20 <= IMG_W) {   // interior fast path
                #pragma unroll
                for (int q = 0; q < 5; ++q) {
                    *(float4*)&p[q * 4] = *(const float4*)&rp[gx0 + q * 4];
                    *(float4*)&t[q * 4] = *(const float4*)&rt[gx0 + q * 4];
                }
            } else {                               // image x-edge: guarded scalar
                #pragma unroll
                for (int q = 0; q < 20; ++q) {
                    int gx = gx0 + q;
                    bool v = (unsigned)gx < IMG_W;
                    p[q] = v ? rp[gx] : 0.f;
                    t[q] = v ? rt[gx] : 0.f;
                }
            }
        } else {
            #pragma unroll
            for (int q = 0; q < 20; ++q) { p[q] = 0.f; t[q] = 0.f; }
        }

        float s1[4], s2[4], s11[4], s22[4], s12[4];
        #pragma unroll
        for (int o = 0; o < 4; ++o) { s1[o]=0.f; s2[o]=0.f; s11[o]=0.f; s22[o]=0.f; s12[o]=0.f; }
        #pragma unroll
        for (int k = 0; k < 11; ++k) {
            float w = wt.w[k];
            #pragma unroll
            for (int o = 0; o < 4; ++o) {
                float pv = p[o + 3 + k], tv = t[o + 3 + k];
                float wp = w * pv, wtv = w * tv;
                s1[o]  += wp;
                s2[o]  += wtv;
                s11[o] += wp * pv;
                s22[o] += wtv * tv;
                s12[o] += wp * tv;
            }
        }
        int ho = r * TILE_X + c4;
        #pragma unroll
        for (int o = 0; o < 4; ++o)
            hAB[ho + o] = make_uint2(pack_bf16x2(s1[o],  s2[o]),
                                     pack_bf16x2(s11[o], s22[o]));
        *(float4*)&hC[ho] = make_float4(s12[0], s12[1], s12[2], s12[3]);
    }
    __syncthreads();

    // ---- Phase C: vertical 11-tap pass + SSIM, f32 compute, 4 rows/thread ----
    const int c  = tid & 63;          // output column (conflict-free)
    const int r0 = (tid >> 6) * 4;    // 8 row-groups x 4 rows = 32 rows exactly
    float a1[4], a2[4], a11[4], a22[4], a12[4];
    #pragma unroll
    for (int o = 0; o < 4; ++o) { a1[o]=0.f; a2[o]=0.f; a11[o]=0.f; a22[o]=0.f; a12[o]=0.f; }

    #pragma unroll
    for (int j = 0; j < 14; ++j) {     // rows r0 .. r0+13 cover outputs r0..r0+3
        int hr = (r0 + j) * TILE_X + c;
        uint2 uab = hAB[hr];           // ds_read_b64, conflict-free
        float v12  = hC[hr];
        float v1  = __uint_as_float(uab.x << 16);          // bf16 -> f32 = shift
        float v2  = __uint_as_float(uab.x & 0xFFFF0000u);
        float v11 = __uint_as_float(uab.y << 16);
        float v22 = __uint_as_float(uab.y & 0xFFFF0000u);
        #pragma unroll
        for (int o = 0; o < 4; ++o) {
            int k = j - o;
            if (k >= 0 && k < 11) {    // compile-time resolved
                float w = wt.w[k];
                a1[o]  += w * v1;
                a2[o]  += w * v2;
                a11[o] += w * v11;
                a22[o] += w * v22;
                a12[o] += w * v12;
            }
        }
    }

    float lsum = 0.f;
    #pragma unroll
    for (int o = 0; o < 4; ++o) {
        float mu1 = a1[o], mu2 = a2[o];
        float m11 = mu1 * mu1, m22 = mu2 * mu2, m12 = mu1 * mu2;
        float sg1 = a11[o] - m11;
        float sg2 = a22[o] - m22;
        float sg12 = a12[o] - m12;
        float num = (2.f * m12 + 1e-4f) * (2.f * sg12 + 9e-4f);
        float den = (m11 + m22 + 1e-4f) * (sg1 + sg2 + 9e-4f);
        lsum += __fdividef(num, den);
    }

    // ---- Block reduction (deterministic) ----
    #pragma unroll
    for (int off = 32; off > 0; off >>= 1) lsum += __shfl_down(lsum, off);
    if ((tid & 63) == 0) wsum[tid >> 6] = lsum;
    __syncthreads();
    if (tid == 0) {
        float bsum = 0.f;
        #pragma unroll
        for (int wv = 0; wv < 8; ++wv) bsum += wsum[wv];
        partials[(blockIdx.z * gridDim.y + blockIdx.y) * gridDim.x + blockIdx.x] = bsum;
    }
}

__global__ void ssim_finalize(const float* __restrict__ partials, float* __restrict__ out)
{
    __shared__ double red[256];
    double s = 0.0;
    for (int i = threadIdx.x; i < NBLOCKS; i += 256) s += (double)partials[i];
    red[threadIdx.x] = s;
    __syncthreads();
    for (int stride = 128; stride > 0; stride >>= 1) {
        if ((int)threadIdx.x < stride) red[threadIdx.x] += red[threadIdx.x + stride];
        __syncthreads();
    }
    if (threadIdx.x == 0) out[0] = (float)(1.0 - red[0] / (double)NPIX);
}

extern "C" void kernel_launch(void* const* d_in, const int* in_sizes, int n_in,
                              void* d_out, int out_size, void* d_ws, size_t ws_size,
                              hipStream_t stream) {
    const float* pred = (const float*)d_in[0];
    const float* targ = (const float*)d_in[1];
    float* out = (float*)d_out;
    float* partials = (float*)d_ws;   // 4096 floats = 16KB, every slot written each call

    Weights wt;
    {
        float g[11];
        float s = 0.f;
        for (int i = 0; i < 11; ++i) {
            float d = (float)(i - 5);
            g[i] = expf(-d * d / (2.f * 1.5f * 1.5f));
            s += g[i];
        }
        for (int i = 0; i < 11; ++i) wt.w[i] = g[i] / s;
    }

    dim3 grid(IMG_W / TILE_X, IMG_H / TILE_Y, 32);   // (8, 16, 32) = 4096 blocks
    ssim_tile_kernel<<<grid, 512, 0, stream>>>(pred, targ, partials, wt);
    ssim_finalize<<<1, 256, 0, stream>>>(partials, out);
}

// Round 7
// 77.245 us; speedup vs baseline: 7.0419x; 1.0291x over previous
//
#include <hip/hip_runtime.h>
#include <cmath>

#define IMG_H 512
#define IMG_W 512
#define TILE_X 64
#define TILE_Y 32
#define LH 42          // TILE_Y + 10 halo rows of horizontal-conv output
#define NBLOCKS (8 * 16 * 32)
#define NPIX (8 * 4 * 512 * 512)

struct Weights { float w[11]; };

// Round-to-nearest-even f32 -> bf16
static __device__ __forceinline__ unsigned bf16_rne(float x) {
    unsigned u = __float_as_uint(x);
    u += 0x7FFFu + ((u >> 16) & 1u);
    return u >> 16;
}
static __device__ __forceinline__ unsigned pack_bf16x2(float a, float b) {
    return bf16_rne(a) | (bf16_rne(b) << 16);
}

// float2 helpers written elementwise so SLP forms v_pk_fma_f32 / v_pk_mul_f32
static __device__ __forceinline__ float2 pkfma(float w, float2 v, float2 acc) {
    acc.x = __builtin_fmaf(w, v.x, acc.x);
    acc.y = __builtin_fmaf(w, v.y, acc.y);
    return acc;
}
static __device__ __forceinline__ float2 pkfma2(float2 w, float2 v, float2 acc) {
    acc.x = __builtin_fmaf(w.x, v.x, acc.x);
    acc.y = __builtin_fmaf(w.y, v.y, acc.y);
    return acc;
}
static __device__ __forceinline__ float2 pkmul(float2 a, float2 b) {
    return make_float2(a.x * b.x, a.y * b.y);
}

// LDS: hAB (2 bf16x2 planes, uint2) 21.0KB + hC (f32) 10.5KB = 32.3KB -> 4 blocks/CU.
// All register math f32/f32x2; storage-only bf16 packing (r4 lesson: no f16 regs).
__global__ __launch_bounds__(512, 4)
void ssim_tile_kernel(const float* __restrict__ pred,
                      const float* __restrict__ targ,
                      float* __restrict__ partials,
                      Weights wt)
{
    __shared__ uint2 hAB[LH * TILE_X];   // .x = (h1,h2) bf16x2, .y = (h11,h22) bf16x2
    __shared__ float hC[LH * TILE_X];    // conv(pt) kept f32
    __shared__ float wsum[8];

    const int tid = threadIdx.x;
    const int x0 = blockIdx.x * TILE_X;
    const int y0 = blockIdx.y * TILE_Y;
    const int plane = blockIdx.z;
    const float* __restrict__ P = pred + (size_t)plane * IMG_H * IMG_W;
    const float* __restrict__ T = targ + (size_t)plane * IMG_H * IMG_W;

    // ---- Phase B: horizontal 11-tap pass directly from global memory ----
    // 42 rows x 16 col-groups (4 outputs each) = 672 work items.
    for (int i = tid; i < LH * 16; i += 512) {
        int r = i >> 4;
        int c4 = (i & 15) * 4;
        int gy = y0 + r - 5;
        float p[20], t[20];
        if ((unsigned)gy < IMG_H) {
            const float* rp = P + gy * IMG_W;
            const float* rt = T + gy * IMG_W;
            int gx0 = x0 + c4 - 8;                 // 16B aligned
            if (gx0 >= 0 && gx0 + 20 <= IMG_W) {   // interior fast path
                #pragma unroll
                for (int q = 0; q < 5; ++q) {
                    *(float4*)&p[q * 4] = *(const float4*)&rp[gx0 + q * 4];
                    *(float4*)&t[q * 4] = *(const float4*)&rt[gx0 + q * 4];
                }
            } else {                               // image x-edge: guarded scalar
                #pragma unroll
                for (int q = 0; q < 20; ++q) {
                    int gx = gx0 + q;
                    bool v = (unsigned)gx < IMG_W;
                    p[q] = v ? rp[gx] : 0.f;
                    t[q] = v ? rt[gx] : 0.f;
                }
            }
        } else {
            #pragma unroll
            for (int q = 0; q < 20; ++q) { p[q] = 0.f; t[q] = 0.f; }
        }

        // Two float2 chains: outputs (0,1) and (2,3)
        float2 s1a = {0,0}, s2a = {0,0}, s11a = {0,0}, s22a = {0,0}, s12a = {0,0};
        float2 s1b = {0,0}, s2b = {0,0}, s11b = {0,0}, s22b = {0,0}, s12b = {0,0};
        #pragma unroll
        for (int k = 0; k < 11; ++k) {
            float w = wt.w[k];
            float2 pva = make_float2(p[3 + k], p[4 + k]);
            float2 tva = make_float2(t[3 + k], t[4 + k]);
            s1a  = pkfma(w, pva, s1a);
            s2a  = pkfma(w, tva, s2a);
            s11a = pkfma(w, pkmul(pva, pva), s11a);
            s22a = pkfma(w, pkmul(tva, tva), s22a);
            s12a = pkfma(w, pkmul(pva, tva), s12a);
            float2 pvb = make_float2(p[5 + k], p[6 + k]);
            float2 tvb = make_float2(t[5 + k], t[6 + k]);
            s1b  = pkfma(w, pvb, s1b);
            s2b  = pkfma(w, tvb, s2b);
            s11b = pkfma(w, pkmul(pvb, pvb), s11b);
            s22b = pkfma(w, pkmul(tvb, tvb), s22b);
            s12b = pkfma(w, pkmul(pvb, tvb), s12b);
        }
        int ho = r * TILE_X + c4;
        hAB[ho + 0] = make_uint2(pack_bf16x2(s1a.x, s2a.x), pack_bf16x2(s11a.x, s22a.x));
        hAB[ho + 1] = make_uint2(pack_bf16x2(s1a.y, s2a.y), pack_bf16x2(s11a.y, s22a.y));
        hAB[ho + 2] = make_uint2(pack_bf16x2(s1b.x, s2b.x), pack_bf16x2(s11b.x, s22b.x));
        hAB[ho + 3] = make_uint2(pack_bf16x2(s1b.y, s2b.y), pack_bf16x2(s11b.y, s22b.y));
        *(float4*)&hC[ho] = make_float4(s12a.x, s12a.y, s12b.x, s12b.y);
    }
    __syncthreads();

    // ---- Phase C: vertical 11-tap pass, paired accumulators + weight pairs ----
    const int c  = tid & 63;          // output column (conflict-free)
    const int r0 = (tid >> 6) * 4;    // 8 row-groups x 4 rows = 32 rows exactly

    // wp[j] = {w[j], w[j-1]}, zero outside [0,11). Indices compile-time after unroll.
    float2 wp[12];
    wp[0] = make_float2(wt.w[0], 0.f);
    #pragma unroll
    for (int j = 1; j <= 10; ++j) wp[j] = make_float2(wt.w[j], wt.w[j - 1]);
    wp[11] = make_float2(0.f, wt.w[10]);

    // Accumulator pairs: a?a = outputs (r0+0, r0+1), a?b = outputs (r0+2, r0+3)
    float2 a1a = {0,0}, a2a = {0,0}, a11a = {0,0}, a22a = {0,0}, a12a = {0,0};
    float2 a1b = {0,0}, a2b = {0,0}, a11b = {0,0}, a22b = {0,0}, a12b = {0,0};

    #pragma unroll
    for (int j = 0; j < 14; ++j) {     // h rows r0 .. r0+13
        int hr = (r0 + j) * TILE_X + c;
        uint2 uab = hAB[hr];           // ds_read_b64, conflict-free
        float v12  = hC[hr];
        float v1  = __uint_as_float(uab.x << 16);          // bf16 -> f32 = shift
        float v2  = __uint_as_float(uab.x & 0xFFFF0000u);
        float v11 = __uint_as_float(uab.y << 16);
        float v22 = __uint_as_float(uab.y & 0xFFFF0000u);
        if (j <= 11) {                 // pair (0,1): taps w[j], w[j-1]
            float2 w2 = wp[j];
            a1a  = pkfma2(w2, make_float2(v1,  v1),  a1a);
            a2a  = pkfma2(w2, make_float2(v2,  v2),  a2a);
            a11a = pkfma2(w2, make_float2(v11, v11), a11a);
            a22a = pkfma2(w2, make_float2(v22, v22), a22a);
            a12a = pkfma2(w2, make_float2(v12, v12), a12a);
        }
        if (j >= 2) {                  // pair (2,3): taps w[j-2], w[j-3]
            float2 w2 = wp[j - 2];
            a1b  = pkfma2(w2, make_float2(v1,  v1),  a1b);
            a2b  = pkfma2(w2, make_float2(v2,  v2),  a2b);
            a11b = pkfma2(w2, make_float2(v11, v11), a11b);
            a22b = pkfma2(w2, make_float2(v22, v22), a22b);
            a12b = pkfma2(w2, make_float2(v12, v12), a12b);
        }
    }

    float mu1_[4] = { a1a.x,  a1a.y,  a1b.x,  a1b.y  };
    float mu2_[4] = { a2a.x,  a2a.y,  a2b.x,  a2b.y  };
    float e11_[4] = { a11a.x, a11a.y, a11b.x, a11b.y };
    float e22_[4] = { a22a.x, a22a.y, a22b.x, a22b.y };
    float e12_[4] = { a12a.x, a12a.y, a12b.x, a12b.y };

    float lsum = 0.f;
    #pragma unroll
    for (int o = 0; o < 4; ++o) {
        float mu1 = mu1_[o], mu2 = mu2_[o];
        float m11 = mu1 * mu1, m22 = mu2 * mu2, m12 = mu1 * mu2;
        float sg1 = e11_[o] - m11;
        float sg2 = e22_[o] - m22;
        float sg12 = e12_[o] - m12;
        float num = (2.f * m12 + 1e-4f) * (2.f * sg12 + 9e-4f);
        float den = (m11 + m22 + 1e-4f) * (sg1 + sg2 + 9e-4f);
        lsum += __fdividef(num, den);
    }

    // ---- Block reduction (deterministic) ----
    #pragma unroll
    for (int off = 32; off > 0; off >>= 1) lsum += __shfl_down(lsum, off);
    if ((tid & 63) == 0) wsum[tid >> 6] = lsum;
    __syncthreads();
    if (tid == 0) {
        float bsum = 0.f;
        #pragma unroll
        for (int wv = 0; wv < 8; ++wv) bsum += wsum[wv];
        partials[(blockIdx.z * gridDim.y + blockIdx.y) * gridDim.x + blockIdx.x] = bsum;
    }
}

__global__ void ssim_finalize(const float* __restrict__ partials, float* __restrict__ out)
{
    __shared__ double red[256];
    double s = 0.0;
    for (int i = threadIdx.x; i < NBLOCKS; i += 256) s += (double)partials[i];
    red[threadIdx.x] = s;
    __syncthreads();
    for (int stride = 128; stride > 0; stride >>= 1) {
        if ((int)threadIdx.x < stride) red[threadIdx.x] += red[threadIdx.x + stride];
        __syncthreads();
    }
    if (threadIdx.x == 0) out[0] = (float)(1.0 - red[0] / (double)NPIX);
}

extern "C" void kernel_launch(void* const* d_in, const int* in_sizes, int n_in,
                              void* d_out, int out_size, void* d_ws, size_t ws_size,
                              hipStream_t stream) {
    const float* pred = (const float*)d_in[0];
    const float* targ = (const float*)d_in[1];
    float* out = (float*)d_out;
    float* partials = (float*)d_ws;   // 4096 floats, every slot written each call

    Weights wt;
    {
        float g[11];
        float s = 0.f;
        for (int i = 0; i < 11; ++i) {
            float d = (float)(i - 5);
            g[i] = expf(-d * d / (2.f * 1.5f * 1.5f));
            s += g[i];
        }
        for (int i = 0; i < 11; ++i) wt.w[i] = g[i] / s;
    }

    dim3 grid(IMG_W / TILE_X, IMG_H / TILE_Y, 32);   // (8, 16, 32) = 4096 blocks
    ssim_tile_kernel<<<grid, 512, 0, stream>>>(pred, targ, partials, wt);
    ssim_finalize<<<1, 256, 0, stream>>>(partials, out);
}